// Round 4
// baseline (272.265 us; speedup 1.0000x reference)
//
#include <hip/hip_runtime.h>

// GMDRSSMStep: h_new = A(x) h + x W_B^T + b_B
//   A(x) = softmax(x W_alpha^T + b_alpha) . {I, swap01, signflip0}
//        + 0.1 * tanh(x W_a^T + b_a).reshape(2,4) row-scaling {c3, c4} cycles
//
// Memory-bound streaming kernel: ~136 MB traffic, roofline ~22 us @ 6.3 TB/s.

constexpr int D = 128;         // D_IN
constexpr int TPB = 256;       // threads per block
constexpr int ROWS = 256;      // rows per block (1 row / thread)
constexpr int CHUNK = 32;      // columns per LDS chunk
constexpr int NCHUNK = D / CHUNK;

__global__ __launch_bounds__(TPB) void gmdr_step_kernel(
    const float* __restrict__ h,
    const float* __restrict__ x,
    const float* __restrict__ W_alpha, const float* __restrict__ b_alpha,
    const float* __restrict__ W_a,     const float* __restrict__ b_a,
    const float* __restrict__ W_B,     const float* __restrict__ b_B,
    float* __restrict__ out, int batch)
{
    // Transposed-float4 chunk tile: xt[c4][row]. 8*257*16B = 32.9 KB.
    // Write banks: (4*c4 + 4*r) % 32 -> 8 lanes per 4-bank group (balanced).
    // Read banks:  (4*t + 4*j) % 32  -> 8 lanes per 4-bank group (balanced).
    __shared__ float4 xt[8][ROWS + 1];

    const int tid = threadIdx.x;
    const long row0 = (long)blockIdx.x * ROWS;

    float acc[15];
#pragma unroll
    for (int o = 0; o < 15; ++o) acc[o] = 0.0f;

    const float4* __restrict__ X4 = reinterpret_cast<const float4*>(x);

    for (int c = 0; c < NCHUNK; ++c) {
        __syncthreads();  // previous chunk's reads done before overwrite
#pragma unroll
        for (int j = 0; j < 8; ++j) {
            const int f  = j * TPB + tid;   // float4 id within the chunk tile
            const int r  = f >> 3;          // row within block
            const int c4 = f & 7;           // float4-column within chunk
            float4 v = make_float4(0.f, 0.f, 0.f, 0.f);
            const long grow = row0 + r;
            if (grow < batch)
                v = X4[grow * (D / 4) + c * 8 + c4];  // 128B contiguous per 8 lanes
            xt[c4][r] = v;
        }
        __syncthreads();

#pragma unroll
        for (int j = 0; j < 8; ++j) {
            const float4 xv = xt[j][tid];
            const int d = c * CHUNK + j * 4;  // uniform -> weights via s_load
#pragma unroll
            for (int o = 0; o < 3; ++o) {
                const float* w = &W_alpha[o * D + d];
                acc[o] += xv.x * w[0] + xv.y * w[1] + xv.z * w[2] + xv.w * w[3];
            }
#pragma unroll
            for (int o = 0; o < 8; ++o) {
                const float* w = &W_a[o * D + d];
                acc[3 + o] += xv.x * w[0] + xv.y * w[1] + xv.z * w[2] + xv.w * w[3];
            }
#pragma unroll
            for (int o = 0; o < 4; ++o) {
                const float* w = &W_B[o * D + d];
                acc[11 + o] += xv.x * w[0] + xv.y * w[1] + xv.z * w[2] + xv.w * w[3];
            }
        }
    }

    const long row = row0 + tid;
    if (row < batch) {
        // softmax over 3 kernel-neighborhood logits
        const float l0 = acc[0] + b_alpha[0];
        const float l1 = acc[1] + b_alpha[1];
        const float l2 = acc[2] + b_alpha[2];
        const float m  = fmaxf(l0, fmaxf(l1, l2));
        const float e0 = __expf(l0 - m);
        const float e1 = __expf(l1 - m);
        const float e2 = __expf(l2 - m);
        const float inv = 1.0f / (e0 + e1 + e2);
        const float al0 = e0 * inv, al1 = e1 * inv, al2 = e2 * inv;

        // low-rank tanh perturbation coefficients, a[r][i] = t[r*4+i]
        float t[8];
#pragma unroll
        for (int i = 0; i < 8; ++i) {
            const float v = acc[3 + i] + b_a[i];
            // tanh(v) = 1 - 2/(exp(2v)+1)  (saturates correctly at +/-inf)
            t[i] = (1.0f - 2.0f / (__expf(2.0f * v) + 1.0f)) * 0.1f;
        }

        const float4 hv = reinterpret_cast<const float4*>(h)[row];

        // A h, closed form:
        //   I:        alpha0 * h
        //   swap01:   alpha1 * [h1,h0,h2,h3]
        //   signflip0:alpha2 * [-h0,h1,h2,h3]
        //   c3 h = [h1,h2,h0,h3], c4 h = [h1,h2,h3,h0]; row i scaled by a[r][i]
        const float asum = al0 + al1 + al2;  // == 1 up to rounding (ref fidelity)
        float r0 = (al0 - al2) * hv.x + al1 * hv.y + (t[0] + t[4]) * hv.y;
        float r1 = al1 * hv.x + (al0 + al2) * hv.y + (t[1] + t[5]) * hv.z;
        float r2 = asum * hv.z + t[2] * hv.x + t[6] * hv.w;
        float r3 = asum * hv.w + t[3] * hv.w + t[7] * hv.x;

        float4 ov;
        ov.x = r0 + acc[11] + b_B[0];
        ov.y = r1 + acc[12] + b_B[1];
        ov.z = r2 + acc[13] + b_B[2];
        ov.w = r3 + acc[14] + b_B[3];
        reinterpret_cast<float4*>(out)[row] = ov;
    }
}

extern "C" void kernel_launch(void* const* d_in, const int* in_sizes, int n_in,
                              void* d_out, int out_size, void* d_ws, size_t ws_size,
                              hipStream_t stream) {
    const float* h       = (const float*)d_in[0];
    const float* x       = (const float*)d_in[1];
    const float* W_alpha = (const float*)d_in[2];
    const float* b_alpha = (const float*)d_in[3];
    const float* W_a     = (const float*)d_in[4];
    const float* b_a     = (const float*)d_in[5];
    const float* W_B     = (const float*)d_in[6];
    const float* b_B     = (const float*)d_in[7];
    float* out = (float*)d_out;

    const int batch = in_sizes[0] / 4;               // h is (B, 4)
    const int grid  = (batch + ROWS - 1) / ROWS;     // B = 262144 -> 1024 blocks

    gmdr_step_kernel<<<grid, TPB, 0, stream>>>(
        h, x, W_alpha, b_alpha, W_a, b_a, W_B, b_B, out, batch);
}

// Round 6
// 234.996 us; speedup vs baseline: 1.1586x; 1.1586x over previous
//
#include <hip/hip_runtime.h>

// GMDRSSMStep: h_new = A(x) h + x W_B^T + b_B
//   A(x) = softmax(x W_alpha^T + b_alpha) . {I, swap01, signflip0}
//        + 0.1 * tanh(x W_a^T + b_a).reshape(2,4) row-scaling {c3, c4} cycles
//
// R4 diagnosis: weight reads from global inside the inner loop dominated
// (22k VALU instrs/wave vs 2k FMAs; 170us @ 5% HBM). Fix: stage all 15x128
// weights in LDS once per block, read with wave-uniform addresses
// (HW broadcast, no bank conflicts, no global traffic in the loop).

constexpr int D = 128;         // D_IN
constexpr int TPB = 256;       // threads per block
constexpr int ROWS = 256;      // rows per block (1 row / thread)
constexpr int CHUNK = 32;      // columns per LDS chunk
constexpr int NCHUNK = D / CHUNK;

__global__ __launch_bounds__(TPB) void gmdr_step_kernel(
    const float* __restrict__ h,
    const float* __restrict__ x,
    const float* __restrict__ W_alpha, const float* __restrict__ b_alpha,
    const float* __restrict__ W_a,     const float* __restrict__ b_a,
    const float* __restrict__ W_B,     const float* __restrict__ b_B,
    float* __restrict__ out, int batch)
{
    // xt: transposed-float4 x tile (bank-balanced, verified conflict-free in R4).
    // w4: all weights, rows concatenated [W_alpha(3) | W_a(8) | W_B(4)] x 128 f32.
    //     Read with uniform addr -> broadcast. Total LDS 40576 B -> 4 blocks/CU.
    __shared__ float4 xt[8][ROWS + 1];
    __shared__ float4 w4[480];   // 15 rows * 32 float4/row

    const int tid = threadIdx.x;
    const long row0 = (long)blockIdx.x * ROWS;

    // ---- one-time weight stage: 480 float4 = [alpha:0..95 | a:96..351 | B:352..479]
    if (tid < 96)  w4[tid]        = reinterpret_cast<const float4*>(W_alpha)[tid];
    w4[96 + tid]                  = reinterpret_cast<const float4*>(W_a)[tid];
    if (tid < 128) w4[352 + tid]  = reinterpret_cast<const float4*>(W_B)[tid];
    // first __syncthreads() inside the chunk loop covers this stage

    float acc[15];
#pragma unroll
    for (int o = 0; o < 15; ++o) acc[o] = 0.0f;

    const float4* __restrict__ X4 = reinterpret_cast<const float4*>(x);

    for (int c = 0; c < NCHUNK; ++c) {
        __syncthreads();  // previous chunk's reads done before overwrite (also fences w4 stage)
#pragma unroll
        for (int j = 0; j < 8; ++j) {
            const int f  = j * TPB + tid;   // float4 id within the chunk tile
            const int r  = f >> 3;          // row within block
            const int c4 = f & 7;           // float4-column within chunk
            float4 v = make_float4(0.f, 0.f, 0.f, 0.f);
            const long grow = row0 + r;
            if (grow < batch)
                v = X4[grow * (D / 4) + c * 8 + c4];  // 128B contiguous per 8 lanes
            xt[c4][r] = v;
        }
        __syncthreads();

#pragma unroll
        for (int j = 0; j < 8; ++j) {
            const float4 xv = xt[j][tid];
            const int d4 = c * 8 + j;       // uniform float4 index into each weight row
#pragma unroll
            for (int o = 0; o < 3; ++o) {
                const float4 w = w4[o * 32 + d4];          // uniform -> LDS broadcast
                acc[o] += xv.x * w.x + xv.y * w.y + xv.z * w.z + xv.w * w.w;
            }
#pragma unroll
            for (int o = 0; o < 8; ++o) {
                const float4 w = w4[96 + o * 32 + d4];
                acc[3 + o] += xv.x * w.x + xv.y * w.y + xv.z * w.z + xv.w * w.w;
            }
#pragma unroll
            for (int o = 0; o < 4; ++o) {
                const float4 w = w4[352 + o * 32 + d4];
                acc[11 + o] += xv.x * w.x + xv.y * w.y + xv.z * w.z + xv.w * w.w;
            }
        }
    }

    const long row = row0 + tid;
    if (row < batch) {
        // softmax over 3 kernel-neighborhood logits
        const float l0 = acc[0] + b_alpha[0];
        const float l1 = acc[1] + b_alpha[1];
        const float l2 = acc[2] + b_alpha[2];
        const float m  = fmaxf(l0, fmaxf(l1, l2));
        const float e0 = __expf(l0 - m);
        const float e1 = __expf(l1 - m);
        const float e2 = __expf(l2 - m);
        const float inv = 1.0f / (e0 + e1 + e2);
        const float al0 = e0 * inv, al1 = e1 * inv, al2 = e2 * inv;

        // low-rank tanh perturbation coefficients, a[r][i] = t[r*4+i]
        float t[8];
#pragma unroll
        for (int i = 0; i < 8; ++i) {
            const float v = acc[3 + i] + b_a[i];
            // tanh(v) = 1 - 2/(exp(2v)+1)  (saturates correctly at +/-inf)
            t[i] = (1.0f - 2.0f / (__expf(2.0f * v) + 1.0f)) * 0.1f;
        }

        const float4 hv = reinterpret_cast<const float4*>(h)[row];

        // A h, closed form:
        //   I:        alpha0 * h
        //   swap01:   alpha1 * [h1,h0,h2,h3]
        //   signflip0:alpha2 * [-h0,h1,h2,h3]
        //   c3 h = [h1,h2,h0,h3], c4 h = [h1,h2,h3,h0]; row i scaled by a[r][i]
        const float asum = al0 + al1 + al2;  // == 1 up to rounding (ref fidelity)
        float r0 = (al0 - al2) * hv.x + al1 * hv.y + (t[0] + t[4]) * hv.y;
        float r1 = al1 * hv.x + (al0 + al2) * hv.y + (t[1] + t[5]) * hv.z;
        float r2 = asum * hv.z + t[2] * hv.x + t[6] * hv.w;
        float r3 = asum * hv.w + t[3] * hv.w + t[7] * hv.x;

        float4 ov;
        ov.x = r0 + acc[11] + b_B[0];
        ov.y = r1 + acc[12] + b_B[1];
        ov.z = r2 + acc[13] + b_B[2];
        ov.w = r3 + acc[14] + b_B[3];
        reinterpret_cast<float4*>(out)[row] = ov;
    }
}

extern "C" void kernel_launch(void* const* d_in, const int* in_sizes, int n_in,
                              void* d_out, int out_size, void* d_ws, size_t ws_size,
                              hipStream_t stream) {
    const float* h       = (const float*)d_in[0];
    const float* x       = (const float*)d_in[1];
    const float* W_alpha = (const float*)d_in[2];
    const float* b_alpha = (const float*)d_in[3];
    const float* W_a     = (const float*)d_in[4];
    const float* b_a     = (const float*)d_in[5];
    const float* W_B     = (const float*)d_in[6];
    const float* b_B     = (const float*)d_in[7];
    float* out = (float*)d_out;

    const int batch = in_sizes[0] / 4;               // h is (B, 4)
    const int grid  = (batch + ROWS - 1) / ROWS;     // B = 262144 -> 1024 blocks

    gmdr_step_kernel<<<grid, TPB, 0, stream>>>(
        h, x, W_alpha, b_alpha, W_a, b_a, W_B, b_B, out, batch);
}

// Round 8
// 207.700 us; speedup vs baseline: 1.3109x; 1.1314x over previous
//
#include <hip/hip_runtime.h>

// GMDRSSMStep via MFMA: P = x @ W_cat^T  (B x 15, padded to 16), then closed-form
// epilogue h_new = A(P_alpha) h + P_B, with tanh low-rank perturbation from P_a.
//
// R6 post-mortem: 1-thread-1-row needs 1920 weight scalars/thread; serving them
// from LDS (120 broadcast ds_read_b128 per wave per chunk) made the LDS pipe the
// bottleneck (~20-55us), occupancy 23%. MFMA holds the ENTIRE weight matrix in
// 8 VGPRs/lane (B-fragments), loaded once per block. A and B frags use identical
// addressing (row = lane&15, 8 consecutive k at (lane>>4)*8 + 32s) so the k-group
// mapping cancels in the dot; C/D layout = m89-verified col=lane&15,
// row=(lane>>4)*4+reg.

using f32x4  = __attribute__((ext_vector_type(4))) float;
using bf16x8 = __attribute__((ext_vector_type(8))) short;

__device__ __forceinline__ short f2bf(float f) {
    union { float f; unsigned u; } v; v.f = f;
    unsigned u = v.u + 0x7fffu + ((v.u >> 16) & 1u);   // round-to-nearest-even
    return (short)(u >> 16);
}

__device__ __forceinline__ bf16x8 pack8(float4 a, float4 b) {
    bf16x8 r;
    r[0] = f2bf(a.x); r[1] = f2bf(a.y); r[2] = f2bf(a.z); r[3] = f2bf(a.w);
    r[4] = f2bf(b.x); r[5] = f2bf(b.y); r[6] = f2bf(b.z); r[7] = f2bf(b.w);
    return r;
}

constexpr int TPB = 64;   // 1 wave per block, 64 rows per block

__global__ __launch_bounds__(TPB) void gmdr_mfma_kernel(
    const float* __restrict__ h,
    const float* __restrict__ x,
    const float* __restrict__ W_alpha, const float* __restrict__ b_alpha,
    const float* __restrict__ W_a,     const float* __restrict__ b_a,
    const float* __restrict__ W_B,     const float* __restrict__ b_B,
    float* __restrict__ out, int batch)
{
    // P-transpose scratch: [tile t][m 0..15][n stride 20], tile stride 328 words.
    // Write (fixed t,r): banks (16g+20r+n)%32 -> 2-way (free). Read: lane L reads
    // tile L>>4 row L&15: banks (8t+20n+w)%32 -> conflict-free. 16B-aligned rows.
    __shared__ float pt[4 * 328];

    const int lane = threadIdx.x;
    const int n16  = lane & 15;     // M/N index of this lane's fragments
    const int g    = lane >> 4;     // k-group
    const long base = (long)blockIdx.x * 64;

    // ---- B-fragments: entire 16x128 weight matrix (rows: 3 alpha | 8 a | 4 B | 1 zero)
    bf16x8 wb[4];
#pragma unroll
    for (int s = 0; s < 4; ++s) wb[s] = (bf16x8){};
    {
        const float* wrow = nullptr;
        if (n16 < 3)       wrow = W_alpha + n16 * 128;
        else if (n16 < 11) wrow = W_a + (n16 - 3) * 128;
        else if (n16 < 15) wrow = W_B + (n16 - 11) * 128;
        if (wrow) {
            const float4* wp = reinterpret_cast<const float4*>(wrow);
#pragma unroll
            for (int s = 0; s < 4; ++s)
                wb[s] = pack8(wp[2 * g + 8 * s], wp[2 * g + 8 * s + 1]);
        }
    }

    const float4* __restrict__ X4 = reinterpret_cast<const float4*>(x);

    // ---- 4 tiles of 16 rows: A-frags stream from x, K=128 in 4 MFMA steps
    f32x4 acc[4];
#pragma unroll
    for (int t = 0; t < 4; ++t) {
        acc[t] = (f32x4){};
        long rowA = base + t * 16 + n16;
        if (rowA >= batch) rowA = batch - 1;          // clamped; result discarded
        const float4* xp = X4 + rowA * 32 + 2 * g;
#pragma unroll
        for (int s = 0; s < 4; ++s) {
            const bf16x8 af = pack8(xp[8 * s], xp[8 * s + 1]);
            acc[t] = __builtin_amdgcn_mfma_f32_16x16x32_bf16(af, wb[s], acc[t], 0, 0, 0);
        }
    }

    // ---- transpose P through LDS: D[m][n] -> each lane owns one row's 16 dots
#pragma unroll
    for (int t = 0; t < 4; ++t)
#pragma unroll
        for (int r = 0; r < 4; ++r)
            pt[t * 328 + (g * 4 + r) * 20 + n16] = acc[t][r];
    __syncthreads();

    const long row = base + lane;
    if (row < batch) {
        const float4* pr = reinterpret_cast<const float4*>(
            &pt[(lane >> 4) * 328 + (lane & 15) * 20]);
        const float4 pa = pr[0], pb = pr[1], pc = pr[2], pd = pr[3];

        // softmax over 3 kernel-neighborhood logits
        const float l0 = pa.x + b_alpha[0];
        const float l1 = pa.y + b_alpha[1];
        const float l2 = pa.z + b_alpha[2];
        const float m  = fmaxf(l0, fmaxf(l1, l2));
        const float e0 = __expf(l0 - m);
        const float e1 = __expf(l1 - m);
        const float e2 = __expf(l2 - m);
        const float inv = 1.0f / (e0 + e1 + e2);
        const float al0 = e0 * inv, al1 = e1 * inv, al2 = e2 * inv;

        // tanh perturbation coeffs t[i] = 0.1*tanh(p[3+i] + b_a[i])
        const float pv[8] = { pa.w, pb.x, pb.y, pb.z, pb.w, pc.x, pc.y, pc.z };
        float tq[8];
#pragma unroll
        for (int i = 0; i < 8; ++i) {
            const float v = pv[i] + b_a[i];
            tq[i] = (1.0f - 2.0f / (__expf(2.0f * v) + 1.0f)) * 0.1f;
        }

        const float4 hv = reinterpret_cast<const float4*>(h)[row];

        // A h closed form (verified R4/R6):
        //   [(a0-a2)h0 + a1 h1,  a1 h0 + (a0+a2)h1,  S h2,  S h3]
        // + [(t0+t4)h1, (t1+t5)h2, t2 h0 + t6 h3, t3 h3 + t7 h0]
        const float asum = al0 + al1 + al2;
        const float r0 = (al0 - al2) * hv.x + al1 * hv.y + (tq[0] + tq[4]) * hv.y;
        const float r1 = al1 * hv.x + (al0 + al2) * hv.y + (tq[1] + tq[5]) * hv.z;
        const float r2 = asum * hv.z + tq[2] * hv.x + tq[6] * hv.w;
        const float r3 = asum * hv.w + tq[3] * hv.w + tq[7] * hv.x;

        float4 ov;
        ov.x = r0 + pc.w + b_B[0];
        ov.y = r1 + pd.x + b_B[1];
        ov.z = r2 + pd.y + b_B[2];
        ov.w = r3 + pd.z + b_B[3];
        reinterpret_cast<float4*>(out)[row] = ov;
    }
}

extern "C" void kernel_launch(void* const* d_in, const int* in_sizes, int n_in,
                              void* d_out, int out_size, void* d_ws, size_t ws_size,
                              hipStream_t stream) {
    const float* h       = (const float*)d_in[0];
    const float* x       = (const float*)d_in[1];
    const float* W_alpha = (const float*)d_in[2];
    const float* b_alpha = (const float*)d_in[3];
    const float* W_a     = (const float*)d_in[4];
    const float* b_a     = (const float*)d_in[5];
    const float* W_B     = (const float*)d_in[6];
    const float* b_B     = (const float*)d_in[7];
    float* out = (float*)d_out;

    const int batch = in_sizes[0] / 4;            // h is (B, 4)
    const int grid  = (batch + TPB - 1) / TPB;    // 64 rows per 1-wave block -> 4096

    gmdr_mfma_kernel<<<grid, TPB, 0, stream>>>(
        h, x, W_alpha, b_alpha, W_a, b_a, W_B, b_B, out, batch);
}